// Round 2
// baseline (849.012 us; speedup 1.0000x reference)
//
#include <hip/hip_runtime.h>
#include <math.h>

#define N_NODES 50000
#define HID 128
#define N_EDGES 600000
#define ROWS_PER_WAVE 8

// ---------------------------------------------------------------- degree ----
__global__ void zero_cnt_kernel(int* cnt, int n) {
    int i = blockIdx.x * blockDim.x + threadIdx.x;
    if (i < n) cnt[i] = 0;
}

__global__ void count_deg_kernel(const int* __restrict__ dst, int* cnt, int e) {
    int i = blockIdx.x * blockDim.x + threadIdx.x;
    if (i < e) atomicAdd(&cnt[dst[i]], 1);
}

__global__ void make_dinv_kernel(const int* __restrict__ cnt, float* dinv, int n) {
    int i = blockIdx.x * blockDim.x + threadIdx.x;
    if (i < n) dinv[i] = rsqrtf((float)(cnt[i] + 1));   // +1 self-loop
}

// ---------------------------------------------------------------- GEMM ------
// H[MxK] = X[MxK] @ W[KxK], K=128. W staged whole in LDS (64KB).
// One wave per row; lane owns cols (lane, lane+64); x-row broadcast via shfl.
__global__ __launch_bounds__(256) void gemm128_kernel(
        const float* __restrict__ X, const float* __restrict__ W,
        float* __restrict__ H, int M) {
    __shared__ float Wl[HID * HID];
    for (int i = threadIdx.x * 4; i < HID * HID; i += 256 * 4) {
        *(float4*)&Wl[i] = *(const float4*)&W[i];
    }
    __syncthreads();

    const int wave = threadIdx.x >> 6;
    const int lane = threadIdx.x & 63;
    const long rowBase = ((long)blockIdx.x * 4 + wave) * ROWS_PER_WAVE;

    for (int r0 = 0; r0 < ROWS_PER_WAVE; ++r0) {
        long r = rowBase + r0;
        if (r >= M) return;
        float xa = X[r * HID + lane];
        float xb = X[r * HID + 64 + lane];
        float acc0 = 0.f, acc1 = 0.f;
#pragma unroll
        for (int k = 0; k < 64; ++k) {
            float xv = __shfl(xa, k);
            acc0 += xv * Wl[k * HID + lane];
            acc1 += xv * Wl[k * HID + 64 + lane];
        }
#pragma unroll
        for (int k = 0; k < 64; ++k) {
            float xv = __shfl(xb, k);
            acc0 += xv * Wl[(64 + k) * HID + lane];
            acc1 += xv * Wl[(64 + k) * HID + 64 + lane];
        }
        H[r * HID + lane] = acc0;
        H[r * HID + 64 + lane] = acc1;
    }
}

// ------------------------------------------------- init: bias + self-loop ---
// out[i,:] = b[:] + h[i,:] * dinv[i]^2   (full overwrite -> no pre-zero needed)
__global__ void init_out_kernel(const float* __restrict__ h,
                                const float* __restrict__ dinv,
                                const float* __restrict__ b,
                                float* __restrict__ out, int n) {
    int i = blockIdx.x * blockDim.x + threadIdx.x;
    int total = n * HID;
    if (i < total) {
        int r = i >> 7;
        int c = i & 127;
        float d = dinv[r];
        out[i] = b[c] + h[i] * d * d;
    }
}

// ---------------------------------------------------------------- scatter ---
// One wave per edge: lane l handles cols l and l+64.
__global__ __launch_bounds__(256) void scatter_kernel(
        const int* __restrict__ src, const int* __restrict__ dst,
        const float* __restrict__ h, const float* __restrict__ dinv,
        float* __restrict__ out, int e) {
    int w = (int)((blockIdx.x * (long)blockDim.x + threadIdx.x) >> 6);
    int lane = threadIdx.x & 63;
    if (w >= e) return;
    int s = src[w];
    int d = dst[w];
    float norm = dinv[s] * dinv[d];
    float v0 = h[(long)s * HID + lane] * norm;
    float v1 = h[(long)s * HID + 64 + lane] * norm;
    atomicAdd(&out[(long)d * HID + lane], v0);
    atomicAdd(&out[(long)d * HID + 64 + lane], v1);
}

// ----------------------------------------------------------- LN + GELU ------
// One wave per row; lane holds elems (lane, lane+64); exact GELU (erf).
__global__ __launch_bounds__(256) void ln_gelu_kernel(
        float* __restrict__ io, const float* __restrict__ g,
        const float* __restrict__ be, int n) {
    int w = (int)((blockIdx.x * (long)blockDim.x + threadIdx.x) >> 6);
    int lane = threadIdx.x & 63;
    if (w >= n) return;
    long base = (long)w * HID;
    float v0 = io[base + lane];
    float v1 = io[base + 64 + lane];
    float s  = v0 + v1;
    float s2 = v0 * v0 + v1 * v1;
#pragma unroll
    for (int off = 32; off >= 1; off >>= 1) {
        s  += __shfl_xor(s,  off);
        s2 += __shfl_xor(s2, off);
    }
    float mu   = s  * (1.0f / 128.0f);
    float var  = s2 * (1.0f / 128.0f) - mu * mu;
    float rstd = rsqrtf(var + 1e-5f);
    float y0 = (v0 - mu) * rstd * g[lane]      + be[lane];
    float y1 = (v1 - mu) * rstd * g[lane + 64] + be[lane + 64];
    io[base + lane]      = 0.5f * y0 * (1.0f + erff(y0 * 0.70710678118654752f));
    io[base + 64 + lane] = 0.5f * y1 * (1.0f + erff(y1 * 0.70710678118654752f));
}

// ---------------------------------------------------------------- launch ----
extern "C" void kernel_launch(void* const* d_in, const int* in_sizes, int n_in,
                              void* d_out, int out_size, void* d_ws, size_t ws_size,
                              hipStream_t stream) {
    const float* x   = (const float*)d_in[0];
    const int*   ei  = (const int*)d_in[1];   // [2, E] pushed as int32 by harness
    const float* W1  = (const float*)d_in[2];
    const float* b1  = (const float*)d_in[3];
    const float* W2  = (const float*)d_in[4];
    const float* b2  = (const float*)d_in[5];
    const float* g1  = (const float*)d_in[6];
    const float* be1 = (const float*)d_in[7];
    const float* g2  = (const float*)d_in[8];
    const float* be2 = (const float*)d_in[9];
    float* out = (float*)d_out;

    const int* src = ei;
    const int* dst = ei + N_EDGES;

    // workspace layout: h [N*HID f32] | cnt [N int] | dinv [N f32]  (~25.9 MB)
    float* h    = (float*)d_ws;
    int*   cnt  = (int*)((char*)d_ws + (size_t)N_NODES * HID * 4);
    float* dinv = (float*)((char*)d_ws + (size_t)N_NODES * HID * 4 + (size_t)N_NODES * 4);

    const int B = 256;
    const int gemm_blocks    = (N_NODES + 4 * ROWS_PER_WAVE - 1) / (4 * ROWS_PER_WAVE);
    const int scatter_blocks = (N_EDGES + 3) / 4;          // 1 wave per edge
    const int rowwave_blocks = (N_NODES + 3) / 4;          // 1 wave per row
    const int elem_blocks    = (N_NODES * HID + B - 1) / B;

    // degree -> dinv (shared by both layers)
    zero_cnt_kernel<<<(N_NODES + B - 1) / B, B, 0, stream>>>(cnt, N_NODES);
    count_deg_kernel<<<(N_EDGES + B - 1) / B, B, 0, stream>>>(dst, cnt, N_EDGES);
    make_dinv_kernel<<<(N_NODES + B - 1) / B, B, 0, stream>>>(cnt, dinv, N_NODES);

    // ---- layer 1 ----
    gemm128_kernel<<<gemm_blocks, B, 0, stream>>>(x, W1, h, N_NODES);
    init_out_kernel<<<elem_blocks, B, 0, stream>>>(h, dinv, b1, out, N_NODES);
    scatter_kernel<<<scatter_blocks, B, 0, stream>>>(src, dst, h, dinv, out, N_EDGES);
    ln_gelu_kernel<<<rowwave_blocks, B, 0, stream>>>(out, g1, be1, N_NODES);

    // ---- layer 2 ---- (out currently holds z1; gemm reads it fully first)
    gemm128_kernel<<<gemm_blocks, B, 0, stream>>>(out, W2, h, N_NODES);
    init_out_kernel<<<elem_blocks, B, 0, stream>>>(h, dinv, b2, out, N_NODES);
    scatter_kernel<<<scatter_blocks, B, 0, stream>>>(src, dst, h, dinv, out, N_EDGES);
    ln_gelu_kernel<<<rowwave_blocks, B, 0, stream>>>(out, g2, be2, N_NODES);
}

// Round 3
// 472.541 us; speedup vs baseline: 1.7967x; 1.7967x over previous
//
#include <hip/hip_runtime.h>
#include <math.h>

#define N_NODES 50000
#define HID 128
#define N_EDGES 600000
#define ROWS_PER_WAVE 8

// ---------------------------------------------------------------- degree ----
__global__ void zero_cnt_kernel(int* cnt, int n) {
    int i = blockIdx.x * blockDim.x + threadIdx.x;
    if (i < n) cnt[i] = 0;
}

__global__ void count_deg_kernel(const int* __restrict__ dst, int* cnt, int e) {
    int i = blockIdx.x * blockDim.x + threadIdx.x;
    if (i < e) atomicAdd(&cnt[dst[i]], 1);
}

__global__ void make_dinv_kernel(const int* __restrict__ cnt, float* dinv, int n) {
    int i = blockIdx.x * blockDim.x + threadIdx.x;
    if (i < n) dinv[i] = rsqrtf((float)(cnt[i] + 1));   // +1 self-loop
}

// ------------------------------------------------------------- CSR scan -----
// two-level exclusive scan of cnt[0..n) -> offs (segment starts)
__global__ __launch_bounds__(256) void block_reduce_kernel(
        const int* __restrict__ cnt, int* __restrict__ bsum, int n) {
    int i = blockIdx.x * 256 + threadIdx.x;
    int v = (i < n) ? cnt[i] : 0;
#pragma unroll
    for (int off = 32; off >= 1; off >>= 1) v += __shfl_xor(v, off);
    __shared__ int ws[4];
    if ((threadIdx.x & 63) == 0) ws[threadIdx.x >> 6] = v;
    __syncthreads();
    if (threadIdx.x == 0) bsum[blockIdx.x] = ws[0] + ws[1] + ws[2] + ws[3];
}

__global__ __launch_bounds__(256) void scan_bsum_kernel(int* bsum, int nb) {
    int t = threadIdx.x;
    int v = (t < nb) ? bsum[t] : 0;
    int x = v;
#pragma unroll
    for (int off = 1; off < 64; off <<= 1) {
        int y = __shfl_up(x, off);
        if ((t & 63) >= off) x += y;
    }
    __shared__ int wtot[4];
    if ((t & 63) == 63) wtot[t >> 6] = x;
    __syncthreads();
    int add = 0;
    for (int w = 0; w < (t >> 6); ++w) add += wtot[w];
    if (t < nb) bsum[t] = x - v + add;   // exclusive
}

__global__ __launch_bounds__(256) void scan_block_kernel(
        const int* __restrict__ cnt, const int* __restrict__ bOff,
        int* __restrict__ offs, int n) {
    int i = blockIdx.x * 256 + threadIdx.x;
    int v = (i < n) ? cnt[i] : 0;
    int x = v;
#pragma unroll
    for (int off = 1; off < 64; off <<= 1) {
        int y = __shfl_up(x, off);
        if ((threadIdx.x & 63) >= off) x += y;
    }
    __shared__ int wtot[4];
    if ((threadIdx.x & 63) == 63) wtot[threadIdx.x >> 6] = x;
    __syncthreads();
    int add = bOff[blockIdx.x];
    for (int w = 0; w < (threadIdx.x >> 6); ++w) add += wtot[w];
    if (i < n) offs[i] = x - v + add;    // exclusive scan = segment start
}

// fill: offs[d] used as atomic cursor; post-fill offs[d] == segment end(d)
__global__ void fill_csr_kernel(const int* __restrict__ src,
                                const int* __restrict__ dst,
                                int* __restrict__ offs,
                                int* __restrict__ srcPerm, int e) {
    int i = blockIdx.x * blockDim.x + threadIdx.x;
    if (i < e) {
        int pos = atomicAdd(&offs[dst[i]], 1);
        srcPerm[pos] = src[i];
    }
}

// ---------------------------------------------------------------- GEMM ------
// hs[MxK] = dinv[r] * (X[MxK] @ W[KxK]), K=128. W staged whole in LDS.
__global__ __launch_bounds__(256) void gemm128_kernel(
        const float* __restrict__ X, const float* __restrict__ W,
        const float* __restrict__ dinv, float* __restrict__ H, int M) {
    __shared__ float Wl[HID * HID];
    for (int i = threadIdx.x * 4; i < HID * HID; i += 256 * 4) {
        *(float4*)&Wl[i] = *(const float4*)&W[i];
    }
    __syncthreads();

    const int wave = threadIdx.x >> 6;
    const int lane = threadIdx.x & 63;
    const long rowBase = ((long)blockIdx.x * 4 + wave) * ROWS_PER_WAVE;

    for (int r0 = 0; r0 < ROWS_PER_WAVE; ++r0) {
        long r = rowBase + r0;
        if (r >= M) return;
        float xa = X[r * HID + lane];
        float xb = X[r * HID + 64 + lane];
        float acc0 = 0.f, acc1 = 0.f;
#pragma unroll
        for (int k = 0; k < 64; ++k) {
            float xv = __shfl(xa, k);
            acc0 += xv * Wl[k * HID + lane];
            acc1 += xv * Wl[k * HID + 64 + lane];
        }
#pragma unroll
        for (int k = 0; k < 64; ++k) {
            float xv = __shfl(xb, k);
            acc0 += xv * Wl[(64 + k) * HID + lane];
            acc1 += xv * Wl[(64 + k) * HID + 64 + lane];
        }
        float dr = dinv[r];
        H[r * HID + lane] = acc0 * dr;
        H[r * HID + 64 + lane] = acc1 * dr;
    }
}

// ------------------------------------------------------------- aggregate ----
// One wave per node d: out[d] = dinv[d]*(hs[d] + sum_{in-edges} hs[s]) + b
__global__ __launch_bounds__(256) void aggregate_kernel(
        const float* __restrict__ hs, const float* __restrict__ dinv,
        const int* __restrict__ offsEnd, const int* __restrict__ srcPerm,
        const float* __restrict__ b, float* __restrict__ out, int n) {
    int d = (int)((blockIdx.x * (long)blockDim.x + threadIdx.x) >> 6);
    int lane = threadIdx.x & 63;
    if (d >= n) return;
    long base = (long)d * HID;
    float acc0 = hs[base + lane];          // self-loop (hs pre-scaled by dinv)
    float acc1 = hs[base + 64 + lane];
    int beg = (d == 0) ? 0 : offsEnd[d - 1];
    int end = offsEnd[d];
    int e = beg;
    for (; e + 1 < end; e += 2) {
        int s0 = srcPerm[e], s1 = srcPerm[e + 1];
        long b0 = (long)s0 * HID, b1 = (long)s1 * HID;
        float a0 = hs[b0 + lane],      c0 = hs[b1 + lane];
        float a1 = hs[b0 + 64 + lane], c1 = hs[b1 + 64 + lane];
        acc0 += a0 + c0;
        acc1 += a1 + c1;
    }
    if (e < end) {
        int s = srcPerm[e];
        acc0 += hs[(long)s * HID + lane];
        acc1 += hs[(long)s * HID + 64 + lane];
    }
    float dd = dinv[d];
    out[base + lane]      = acc0 * dd + b[lane];
    out[base + 64 + lane] = acc1 * dd + b[lane + 64];
}

// ----------------------------------------------------------- LN + GELU ------
__global__ __launch_bounds__(256) void ln_gelu_kernel(
        float* __restrict__ io, const float* __restrict__ g,
        const float* __restrict__ be, int n) {
    int w = (int)((blockIdx.x * (long)blockDim.x + threadIdx.x) >> 6);
    int lane = threadIdx.x & 63;
    if (w >= n) return;
    long base = (long)w * HID;
    float v0 = io[base + lane];
    float v1 = io[base + 64 + lane];
    float s  = v0 + v1;
    float s2 = v0 * v0 + v1 * v1;
#pragma unroll
    for (int off = 32; off >= 1; off >>= 1) {
        s  += __shfl_xor(s,  off);
        s2 += __shfl_xor(s2, off);
    }
    float mu   = s  * (1.0f / 128.0f);
    float var  = s2 * (1.0f / 128.0f) - mu * mu;
    float rstd = rsqrtf(var + 1e-5f);
    float y0 = (v0 - mu) * rstd * g[lane]      + be[lane];
    float y1 = (v1 - mu) * rstd * g[lane + 64] + be[lane + 64];
    io[base + lane]      = 0.5f * y0 * (1.0f + erff(y0 * 0.70710678118654752f));
    io[base + 64 + lane] = 0.5f * y1 * (1.0f + erff(y1 * 0.70710678118654752f));
}

// ---------------------------------------------------------------- launch ----
extern "C" void kernel_launch(void* const* d_in, const int* in_sizes, int n_in,
                              void* d_out, int out_size, void* d_ws, size_t ws_size,
                              hipStream_t stream) {
    const float* x   = (const float*)d_in[0];
    const int*   ei  = (const int*)d_in[1];   // [2, E] int32 (harness convention)
    const float* W1  = (const float*)d_in[2];
    const float* b1  = (const float*)d_in[3];
    const float* W2  = (const float*)d_in[4];
    const float* b2  = (const float*)d_in[5];
    const float* g1  = (const float*)d_in[6];
    const float* be1 = (const float*)d_in[7];
    const float* g2  = (const float*)d_in[8];
    const float* be2 = (const float*)d_in[9];
    float* out = (float*)d_out;

    const int* src = ei;
    const int* dst = ei + N_EDGES;

    // ws layout (floats/ints, 4B each):
    // hs [N*HID] | srcPerm [E] | dinv [N] | offs [N] | cnt [N] | bsum [256]
    float* hs      = (float*)d_ws;
    int*   srcPerm = (int*)  ((char*)d_ws + (size_t)(N_NODES * HID) * 4);
    float* dinv    = (float*)((char*)srcPerm + (size_t)N_EDGES * 4);
    int*   offs    = (int*)  ((char*)dinv + (size_t)N_NODES * 4);
    int*   cnt     = (int*)  ((char*)offs + (size_t)N_NODES * 4);
    int*   bsum    = (int*)  ((char*)cnt  + (size_t)N_NODES * 4);

    const int B = 256;
    const int nodeB  = (N_NODES + B - 1) / B;           // 196
    const int edgeB  = (N_EDGES + B - 1) / B;
    const int gemm_blocks    = (N_NODES + 4 * ROWS_PER_WAVE - 1) / (4 * ROWS_PER_WAVE);
    const int rowwave_blocks = (N_NODES + 3) / 4;       // 1 wave per node

    // degree -> dinv, CSR
    zero_cnt_kernel<<<nodeB, B, 0, stream>>>(cnt, N_NODES);
    count_deg_kernel<<<edgeB, B, 0, stream>>>(dst, cnt, N_EDGES);
    make_dinv_kernel<<<nodeB, B, 0, stream>>>(cnt, dinv, N_NODES);
    block_reduce_kernel<<<nodeB, B, 0, stream>>>(cnt, bsum, N_NODES);
    scan_bsum_kernel<<<1, B, 0, stream>>>(bsum, nodeB);
    scan_block_kernel<<<nodeB, B, 0, stream>>>(cnt, bsum, offs, N_NODES);
    fill_csr_kernel<<<edgeB, B, 0, stream>>>(src, dst, offs, srcPerm, N_EDGES);
    // post-fill: offs[d] == end of segment d

    // ---- layer 1 ----
    gemm128_kernel<<<gemm_blocks, B, 0, stream>>>(x, W1, dinv, hs, N_NODES);
    aggregate_kernel<<<rowwave_blocks, B, 0, stream>>>(hs, dinv, offs, srcPerm, b1, out, N_NODES);
    ln_gelu_kernel<<<rowwave_blocks, B, 0, stream>>>(out, g1, be1, N_NODES);

    // ---- layer 2 ----
    gemm128_kernel<<<gemm_blocks, B, 0, stream>>>(out, W2, dinv, hs, N_NODES);
    aggregate_kernel<<<rowwave_blocks, B, 0, stream>>>(hs, dinv, offs, srcPerm, b2, out, N_NODES);
    ln_gelu_kernel<<<rowwave_blocks, B, 0, stream>>>(out, g2, be2, N_NODES);
}

// Round 4
// 250.179 us; speedup vs baseline: 3.3936x; 1.8888x over previous
//
#include <hip/hip_runtime.h>
#include <math.h>

#define N_NODES 50000
#define HID 128
#define N_EDGES 600000
#define GBM 64   // gemm rows per block

// ---------------------------------------------------------------- degree ----
__global__ void zero_cnt_kernel(int* cnt, int n) {
    int i = blockIdx.x * blockDim.x + threadIdx.x;
    if (i < n) cnt[i] = 0;
}

__global__ void count_deg_kernel(const int* __restrict__ dst, int* cnt, int e) {
    int i = blockIdx.x * blockDim.x + threadIdx.x;
    if (i < e) atomicAdd(&cnt[dst[i]], 1);
}

__global__ void make_dinv_kernel(const int* __restrict__ cnt, float* dinv, int n) {
    int i = blockIdx.x * blockDim.x + threadIdx.x;
    if (i < n) dinv[i] = rsqrtf((float)(cnt[i] + 1));   // +1 self-loop
}

// ------------------------------------------------------------- CSR scan -----
__global__ __launch_bounds__(256) void block_reduce_kernel(
        const int* __restrict__ cnt, int* __restrict__ bsum, int n) {
    int i = blockIdx.x * 256 + threadIdx.x;
    int v = (i < n) ? cnt[i] : 0;
#pragma unroll
    for (int off = 32; off >= 1; off >>= 1) v += __shfl_xor(v, off);
    __shared__ int ws[4];
    if ((threadIdx.x & 63) == 0) ws[threadIdx.x >> 6] = v;
    __syncthreads();
    if (threadIdx.x == 0) bsum[blockIdx.x] = ws[0] + ws[1] + ws[2] + ws[3];
}

__global__ __launch_bounds__(256) void scan_bsum_kernel(int* bsum, int nb) {
    int t = threadIdx.x;
    int v = (t < nb) ? bsum[t] : 0;
    int x = v;
#pragma unroll
    for (int off = 1; off < 64; off <<= 1) {
        int y = __shfl_up(x, off);
        if ((t & 63) >= off) x += y;
    }
    __shared__ int wtot[4];
    if ((t & 63) == 63) wtot[t >> 6] = x;
    __syncthreads();
    int add = 0;
    for (int w = 0; w < (t >> 6); ++w) add += wtot[w];
    if (t < nb) bsum[t] = x - v + add;   // exclusive
}

__global__ __launch_bounds__(256) void scan_block_kernel(
        const int* __restrict__ cnt, const int* __restrict__ bOff,
        int* __restrict__ offs, int n) {
    int i = blockIdx.x * 256 + threadIdx.x;
    int v = (i < n) ? cnt[i] : 0;
    int x = v;
#pragma unroll
    for (int off = 1; off < 64; off <<= 1) {
        int y = __shfl_up(x, off);
        if ((threadIdx.x & 63) >= off) x += y;
    }
    __shared__ int wtot[4];
    if ((threadIdx.x & 63) == 63) wtot[threadIdx.x >> 6] = x;
    __syncthreads();
    int add = bOff[blockIdx.x];
    for (int w = 0; w < (threadIdx.x >> 6); ++w) add += wtot[w];
    if (i < n) offs[i] = x - v + add;    // exclusive scan = segment start
}

__global__ void fill_csr_kernel(const int* __restrict__ src,
                                const int* __restrict__ dst,
                                int* __restrict__ offs,
                                int* __restrict__ srcPerm, int e) {
    int i = blockIdx.x * blockDim.x + threadIdx.x;
    if (i < e) {
        int pos = atomicAdd(&offs[dst[i]], 1);
        srcPerm[pos] = src[i];
    }
}

// ---------------------------------------------------------------- GEMM ------
// hs[r][:] = dinv[r] * (X[r][:] @ W), M x 128 @ 128 x 128.
// Register-tiled: block = 64 rows x 128 cols, thread = 4 rows x 8 cols.
// W in LDS, padded chunk layout: float4 slot(k, c4) = k*35 + c4 + (c4>>3).
// Read pattern (16 col-groups x b128) -> 2-way bank aliasing only (free).
__global__ __launch_bounds__(256) void gemm128_rt_kernel(
        const float* __restrict__ X, const float* __restrict__ W,
        const float* __restrict__ dinv, float* __restrict__ H, int M) {
    __shared__ float4 Wl[128 * 35];
    const float4* W4 = (const float4*)W;
    for (int i = threadIdx.x; i < 128 * 32; i += 256) {
        int k = i >> 5, c4 = i & 31;
        Wl[k * 35 + c4 + (c4 >> 3)] = W4[i];
    }
    __syncthreads();

    const int cg = threadIdx.x & 15;          // cols cg*8 .. cg*8+7
    const int rg = threadIdx.x >> 4;          // rows rg*4 .. rg*4+3
    const long row0 = (long)blockIdx.x * GBM + rg * 4;
    if (row0 >= M) return;                    // M % 4 == 0 -> no partial groups

    const int wslot = cg * 2 + (cg >> 2);     // first float4 slot within k-row
    const float4* X4 = (const float4*)X;      // X4[r*32 + kc]

    float acc[4][8];
#pragma unroll
    for (int i = 0; i < 4; ++i)
#pragma unroll
        for (int j = 0; j < 8; ++j) acc[i][j] = 0.f;

    for (int kc = 0; kc < 32; ++kc) {
        float4 av[4];
#pragma unroll
        for (int i = 0; i < 4; ++i) av[i] = X4[(row0 + i) * 32 + kc];
#pragma unroll
        for (int kk = 0; kk < 4; ++kk) {
            float4 w0 = Wl[(kc * 4 + kk) * 35 + wslot];
            float4 w1 = Wl[(kc * 4 + kk) * 35 + wslot + 1];
#pragma unroll
            for (int i = 0; i < 4; ++i) {
                float a = (kk == 0) ? av[i].x : (kk == 1) ? av[i].y
                        : (kk == 2) ? av[i].z : av[i].w;
                acc[i][0] += a * w0.x; acc[i][1] += a * w0.y;
                acc[i][2] += a * w0.z; acc[i][3] += a * w0.w;
                acc[i][4] += a * w1.x; acc[i][5] += a * w1.y;
                acc[i][6] += a * w1.z; acc[i][7] += a * w1.w;
            }
        }
    }

    float4* H4 = (float4*)H;
#pragma unroll
    for (int i = 0; i < 4; ++i) {
        float dr = dinv[row0 + i];
        float4 o0 = { acc[i][0] * dr, acc[i][1] * dr, acc[i][2] * dr, acc[i][3] * dr };
        float4 o1 = { acc[i][4] * dr, acc[i][5] * dr, acc[i][6] * dr, acc[i][7] * dr };
        H4[(row0 + i) * 32 + cg * 2]     = o0;
        H4[(row0 + i) * 32 + cg * 2 + 1] = o1;
    }
}

// ------------------------------------------ aggregate + LN + GELU (fused) ---
// One wave per node d: t = dinv[d]*(hs[d] + sum_in hs[s]) + b; out = gelu(ln(t))
__global__ __launch_bounds__(256) void agg_ln_gelu_kernel(
        const float* __restrict__ hs, const float* __restrict__ dinv,
        const int* __restrict__ offsEnd, const int* __restrict__ srcPerm,
        const float* __restrict__ b, const float* __restrict__ g,
        const float* __restrict__ be, float* __restrict__ out, int n) {
    int d = (int)((blockIdx.x * (long)blockDim.x + threadIdx.x) >> 6);
    int lane = threadIdx.x & 63;
    if (d >= n) return;
    long base = (long)d * HID;
    float acc0 = hs[base + lane];             // self-loop (hs pre-scaled)
    float acc1 = hs[base + 64 + lane];
    int beg = (d == 0) ? 0 : offsEnd[d - 1];
    int end = offsEnd[d];
    int e = beg;
    for (; e + 3 < end; e += 4) {
        int s0 = srcPerm[e], s1 = srcPerm[e + 1];
        int s2 = srcPerm[e + 2], s3 = srcPerm[e + 3];
        long b0 = (long)s0 * HID, b1 = (long)s1 * HID;
        long b2 = (long)s2 * HID, b3 = (long)s3 * HID;
        float p0 = hs[b0 + lane],      p1 = hs[b1 + lane];
        float p2 = hs[b2 + lane],      p3 = hs[b3 + lane];
        float q0 = hs[b0 + 64 + lane], q1 = hs[b1 + 64 + lane];
        float q2 = hs[b2 + 64 + lane], q3 = hs[b3 + 64 + lane];
        acc0 += (p0 + p1) + (p2 + p3);
        acc1 += (q0 + q1) + (q2 + q3);
    }
    for (; e < end; ++e) {
        int s = srcPerm[e];
        acc0 += hs[(long)s * HID + lane];
        acc1 += hs[(long)s * HID + 64 + lane];
    }
    float dd = dinv[d];
    float v0 = acc0 * dd + b[lane];
    float v1 = acc1 * dd + b[lane + 64];

    // LayerNorm over the 128 row elems held as (v0, v1) across the wave
    float s  = v0 + v1;
    float s2 = v0 * v0 + v1 * v1;
#pragma unroll
    for (int off = 32; off >= 1; off >>= 1) {
        s  += __shfl_xor(s,  off);
        s2 += __shfl_xor(s2, off);
    }
    float mu   = s  * (1.0f / 128.0f);
    float var  = s2 * (1.0f / 128.0f) - mu * mu;
    float rstd = rsqrtf(var + 1e-5f);
    float y0 = (v0 - mu) * rstd * g[lane]      + be[lane];
    float y1 = (v1 - mu) * rstd * g[lane + 64] + be[lane + 64];
    out[base + lane]      = 0.5f * y0 * (1.0f + erff(y0 * 0.70710678118654752f));
    out[base + 64 + lane] = 0.5f * y1 * (1.0f + erff(y1 * 0.70710678118654752f));
}

// ---------------------------------------------------------------- launch ----
extern "C" void kernel_launch(void* const* d_in, const int* in_sizes, int n_in,
                              void* d_out, int out_size, void* d_ws, size_t ws_size,
                              hipStream_t stream) {
    const float* x   = (const float*)d_in[0];
    const int*   ei  = (const int*)d_in[1];   // [2, E] int32
    const float* W1  = (const float*)d_in[2];
    const float* b1  = (const float*)d_in[3];
    const float* W2  = (const float*)d_in[4];
    const float* b2  = (const float*)d_in[5];
    const float* g1  = (const float*)d_in[6];
    const float* be1 = (const float*)d_in[7];
    const float* g2  = (const float*)d_in[8];
    const float* be2 = (const float*)d_in[9];
    float* out = (float*)d_out;

    const int* src = ei;
    const int* dst = ei + N_EDGES;

    // ws layout: hs [N*HID] | srcPerm [E] | dinv [N] | offs [N] | cnt [N] | bsum [256]
    float* hs      = (float*)d_ws;
    int*   srcPerm = (int*)  ((char*)d_ws + (size_t)(N_NODES * HID) * 4);
    float* dinv    = (float*)((char*)srcPerm + (size_t)N_EDGES * 4);
    int*   offs    = (int*)  ((char*)dinv + (size_t)N_NODES * 4);
    int*   cnt     = (int*)  ((char*)offs + (size_t)N_NODES * 4);
    int*   bsum    = (int*)  ((char*)cnt  + (size_t)N_NODES * 4);

    const int B = 256;
    const int nodeB = (N_NODES + B - 1) / B;            // 196
    const int edgeB = (N_EDGES + B - 1) / B;
    const int gemm_blocks    = (N_NODES + GBM - 1) / GBM;   // 782
    const int rowwave_blocks = (N_NODES + 3) / 4;       // 1 wave per node

    // degree -> dinv, CSR
    zero_cnt_kernel<<<nodeB, B, 0, stream>>>(cnt, N_NODES);
    count_deg_kernel<<<edgeB, B, 0, stream>>>(dst, cnt, N_EDGES);
    make_dinv_kernel<<<nodeB, B, 0, stream>>>(cnt, dinv, N_NODES);
    block_reduce_kernel<<<nodeB, B, 0, stream>>>(cnt, bsum, N_NODES);
    scan_bsum_kernel<<<1, B, 0, stream>>>(bsum, nodeB);
    scan_block_kernel<<<nodeB, B, 0, stream>>>(cnt, bsum, offs, N_NODES);
    fill_csr_kernel<<<edgeB, B, 0, stream>>>(src, dst, offs, srcPerm, N_EDGES);
    // post-fill: offs[d] == end of segment d

    // ---- layer 1 ----
    gemm128_rt_kernel<<<gemm_blocks, B, 0, stream>>>(x, W1, dinv, hs, N_NODES);
    agg_ln_gelu_kernel<<<rowwave_blocks, B, 0, stream>>>(hs, dinv, offs, srcPerm,
                                                         b1, g1, be1, out, N_NODES);
    // ---- layer 2 ----
    gemm128_rt_kernel<<<gemm_blocks, B, 0, stream>>>(out, W2, dinv, hs, N_NODES);
    agg_ln_gelu_kernel<<<rowwave_blocks, B, 0, stream>>>(hs, dinv, offs, srcPerm,
                                                         b2, g2, be2, out, N_NODES);
}

// Round 5
// 184.074 us; speedup vs baseline: 4.6124x; 1.3591x over previous
//
#include <hip/hip_runtime.h>
#include <math.h>

#define N_NODES 50000
#define HID 128
#define N_EDGES 600000

typedef __attribute__((ext_vector_type(8))) short s16x8;
typedef __attribute__((ext_vector_type(4))) float f32x4;

// RNE float -> bf16 bits (finite inputs only)
__device__ __forceinline__ ushort f2b(float f) {
    uint x = __builtin_bit_cast(uint, f);
    uint r = (x + 0x7FFFu + ((x >> 16) & 1u)) >> 16;
    return (ushort)r;
}
__device__ __forceinline__ float b2f(ushort u) {
    return __builtin_bit_cast(float, (uint)u << 16);
}

// ---------------------------------------------------------------- degree ----
__global__ void zero_cnt_kernel(int* cnt, int n) {
    int i = blockIdx.x * blockDim.x + threadIdx.x;
    if (i < n) cnt[i] = 0;
}

__global__ void count_deg_kernel(const int* __restrict__ dst, int* cnt, int e) {
    int i = blockIdx.x * blockDim.x + threadIdx.x;
    if (i < e) atomicAdd(&cnt[dst[i]], 1);
}

// fused: dinv[i] = rsqrt(cnt[i]+1)  AND  bsum[blk] = sum(cnt) for the scan
__global__ __launch_bounds__(256) void reduce_dinv_kernel(
        const int* __restrict__ cnt, float* __restrict__ dinv,
        int* __restrict__ bsum, int n) {
    int i = blockIdx.x * 256 + threadIdx.x;
    int v = (i < n) ? cnt[i] : 0;
    if (i < n) dinv[i] = rsqrtf((float)(v + 1));   // +1 self-loop
#pragma unroll
    for (int off = 32; off >= 1; off >>= 1) v += __shfl_xor(v, off);
    __shared__ int ws[4];
    if ((threadIdx.x & 63) == 0) ws[threadIdx.x >> 6] = v;
    __syncthreads();
    if (threadIdx.x == 0) bsum[blockIdx.x] = ws[0] + ws[1] + ws[2] + ws[3];
}

__global__ __launch_bounds__(256) void scan_bsum_kernel(int* bsum, int nb) {
    int t = threadIdx.x;
    int v = (t < nb) ? bsum[t] : 0;
    int x = v;
#pragma unroll
    for (int off = 1; off < 64; off <<= 1) {
        int y = __shfl_up(x, off);
        if ((t & 63) >= off) x += y;
    }
    __shared__ int wtot[4];
    if ((t & 63) == 63) wtot[t >> 6] = x;
    __syncthreads();
    int add = 0;
    for (int w = 0; w < (t >> 6); ++w) add += wtot[w];
    if (t < nb) bsum[t] = x - v + add;   // exclusive
}

__global__ __launch_bounds__(256) void scan_block_kernel(
        const int* __restrict__ cnt, const int* __restrict__ bOff,
        int* __restrict__ offs, int n) {
    int i = blockIdx.x * 256 + threadIdx.x;
    int v = (i < n) ? cnt[i] : 0;
    int x = v;
#pragma unroll
    for (int off = 1; off < 64; off <<= 1) {
        int y = __shfl_up(x, off);
        if ((threadIdx.x & 63) >= off) x += y;
    }
    __shared__ int wtot[4];
    if ((threadIdx.x & 63) == 63) wtot[threadIdx.x >> 6] = x;
    __syncthreads();
    int add = bOff[blockIdx.x];
    for (int w = 0; w < (threadIdx.x >> 6); ++w) add += wtot[w];
    if (i < n) offs[i] = x - v + add;    // exclusive scan = segment start
}

__global__ void fill_csr_kernel(const int* __restrict__ src,
                                const int* __restrict__ dst,
                                int* __restrict__ offs,
                                int* __restrict__ srcPerm, int e) {
    int i = blockIdx.x * blockDim.x + threadIdx.x;
    if (i < e) {
        int pos = atomicAdd(&offs[dst[i]], 1);
        srcPerm[pos] = src[i];
    }
}

// ------------------------------------------------------------ MFMA GEMM -----
// H(bf16)[r][c] = dinv[r] * (A[r][:] @ W[:][c]),  M x 128 @ 128 x 128.
// Per wave: 16 rows x 128 cols via 8 col-tiles x 4 k-steps of
// v_mfma_f32_16x16x32_bf16. Layouts (learn_hip m89-verified family):
//   A: row=lane&15, k=(lane>>4)*8+j   B: col=lane&15, same k
//   C/D: col=lane&15, row=(lane>>4)*4+reg
// W staged transposed in LDS, Wt[n][k], pitch 136 bf16 (272 B):
//   b128 reads: 16 lanes stride 272B -> banks 4n%32 -> 2-way alias = free.
template<bool AFP32>
__global__ __launch_bounds__(256) void gemm_mfma_kernel(
        const void* __restrict__ Ap, const float* __restrict__ W,
        const float* __restrict__ dinv, ushort* __restrict__ H, int M) {
    __shared__ ushort Wt[HID * 136];
    uint* Wt32 = (uint*)Wt;
    for (int idx = threadIdx.x; idx < HID * 64; idx += 256) {
        int k2 = idx >> 7;            // k pair 0..63
        int n  = idx & 127;
        float w0 = W[(2 * k2) * HID + n];
        float w1 = W[(2 * k2 + 1) * HID + n];
        Wt32[n * 68 + k2] = (uint)f2b(w0) | ((uint)f2b(w1) << 16);
    }
    __syncthreads();

    const int l  = threadIdx.x & 63;
    const int wv = threadIdx.x >> 6;
    const int r0 = blockIdx.x * 64 + wv * 16;
    if (r0 >= M) return;              // M % 16 == 0 -> whole waves only
    const int arow = r0 + (l & 15);
    const int kg = l >> 4;            // 0..3

    s16x8 afr[4];
    if (AFP32) {
        const float* A = (const float*)Ap + (long)arow * HID;
#pragma unroll
        for (int ks = 0; ks < 4; ++ks) {
            int k0 = ks * 32 + kg * 8;
            float4 a0 = *(const float4*)(A + k0);
            float4 a1 = *(const float4*)(A + k0 + 4);
            s16x8 v;
            v[0] = (short)f2b(a0.x); v[1] = (short)f2b(a0.y);
            v[2] = (short)f2b(a0.z); v[3] = (short)f2b(a0.w);
            v[4] = (short)f2b(a1.x); v[5] = (short)f2b(a1.y);
            v[6] = (short)f2b(a1.z); v[7] = (short)f2b(a1.w);
            afr[ks] = v;
        }
    } else {
        const ushort* A = (const ushort*)Ap + (long)arow * HID;
#pragma unroll
        for (int ks = 0; ks < 4; ++ks) {
            afr[ks] = *(const s16x8*)(A + ks * 32 + kg * 8);
        }
    }

    float drv[4];
#pragma unroll
    for (int q = 0; q < 4; ++q) drv[q] = dinv[r0 + kg * 4 + q];

    f32x4 acc[8];
#pragma unroll
    for (int ct = 0; ct < 8; ++ct) acc[ct] = (f32x4)(0.f);

#pragma unroll
    for (int ct = 0; ct < 8; ++ct) {
        const ushort* Wrow = Wt + (ct * 16 + (l & 15)) * 136;
#pragma unroll
        for (int ks = 0; ks < 4; ++ks) {
            s16x8 bfr = *(const s16x8*)(Wrow + ks * 32 + kg * 8);
            acc[ct] = __builtin_amdgcn_mfma_f32_16x16x32_bf16(
                          afr[ks], bfr, acc[ct], 0, 0, 0);
        }
    }

#pragma unroll
    for (int ct = 0; ct < 8; ++ct) {
        int col = ct * 16 + (l & 15);
#pragma unroll
        for (int q = 0; q < 4; ++q) {
            int row = r0 + kg * 4 + q;
            H[(long)row * HID + col] = f2b(acc[ct][q] * drv[q]);
        }
    }
}

// ------------------------------------------ aggregate + LN + GELU (fused) ---
// One wave per node d; lane l owns cols (2l, 2l+1) packed as one u32 of bf16x2.
// t = dinv[d]*(hs[d] + sum_in hs[s]) + b;  out = gelu(ln(t)).
template<bool OUT_F32>
__global__ __launch_bounds__(256) void agg_ln_gelu_kernel(
        const uint* __restrict__ hs2, const float* __restrict__ dinv,
        const int* __restrict__ offsEnd, const int* __restrict__ srcPerm,
        const float* __restrict__ b, const float* __restrict__ g,
        const float* __restrict__ be,
        float* __restrict__ outf, uint* __restrict__ outb, int n) {
    int d = (int)((blockIdx.x * (long)blockDim.x + threadIdx.x) >> 6);
    int l = threadIdx.x & 63;
    if (d >= n) return;

    uint u = hs2[(long)d * 64 + l];                  // self-loop (pre-scaled)
    float acc0 = b2f((ushort)u);
    float acc1 = b2f((ushort)(u >> 16));

    int beg = (d == 0) ? 0 : offsEnd[d - 1];
    int end = offsEnd[d];
    int e = beg;
    for (; e + 3 < end; e += 4) {
        int s0 = srcPerm[e],     s1 = srcPerm[e + 1];
        int s2 = srcPerm[e + 2], s3 = srcPerm[e + 3];
        uint u0 = hs2[(long)s0 * 64 + l];
        uint u1 = hs2[(long)s1 * 64 + l];
        uint u2 = hs2[(long)s2 * 64 + l];
        uint u3 = hs2[(long)s3 * 64 + l];
        acc0 += (b2f((ushort)u0) + b2f((ushort)u1))
              + (b2f((ushort)u2) + b2f((ushort)u3));
        acc1 += (b2f((ushort)(u0 >> 16)) + b2f((ushort)(u1 >> 16)))
              + (b2f((ushort)(u2 >> 16)) + b2f((ushort)(u3 >> 16)));
    }
    for (; e < end; ++e) {
        uint ue = hs2[(long)srcPerm[e] * 64 + l];
        acc0 += b2f((ushort)ue);
        acc1 += b2f((ushort)(ue >> 16));
    }

    float dd = dinv[d];
    float2 bb = *(const float2*)&b[2 * l];
    float v0 = acc0 * dd + bb.x;
    float v1 = acc1 * dd + bb.y;

    float s  = v0 + v1;
    float s2 = v0 * v0 + v1 * v1;
#pragma unroll
    for (int off = 32; off >= 1; off >>= 1) {
        s  += __shfl_xor(s,  off);
        s2 += __shfl_xor(s2, off);
    }
    float mu   = s  * (1.0f / 128.0f);
    float var  = s2 * (1.0f / 128.0f) - mu * mu;
    float rstd = rsqrtf(var + 1e-5f);
    float2 gg = *(const float2*)&g[2 * l];
    float2 ee = *(const float2*)&be[2 * l];
    float y0 = (v0 - mu) * rstd * gg.x + ee.x;
    float y1 = (v1 - mu) * rstd * gg.y + ee.y;
    float o0 = 0.5f * y0 * (1.0f + erff(y0 * 0.70710678118654752f));
    float o1 = 0.5f * y1 * (1.0f + erff(y1 * 0.70710678118654752f));

    if (OUT_F32) {
        float2 o = { o0, o1 };
        *(float2*)&outf[(long)d * HID + 2 * l] = o;
    } else {
        outb[(long)d * 64 + l] = (uint)f2b(o0) | ((uint)f2b(o1) << 16);
    }
}

// ---------------------------------------------------------------- launch ----
extern "C" void kernel_launch(void* const* d_in, const int* in_sizes, int n_in,
                              void* d_out, int out_size, void* d_ws, size_t ws_size,
                              hipStream_t stream) {
    const float* x   = (const float*)d_in[0];
    const int*   ei  = (const int*)d_in[1];   // [2, E] int32
    const float* W1  = (const float*)d_in[2];
    const float* b1  = (const float*)d_in[3];
    const float* W2  = (const float*)d_in[4];
    const float* b2  = (const float*)d_in[5];
    const float* g1  = (const float*)d_in[6];
    const float* be1 = (const float*)d_in[7];
    const float* g2  = (const float*)d_in[8];
    const float* be2 = (const float*)d_in[9];
    float* out = (float*)d_out;

    const int* src = ei;
    const int* dst = ei + N_EDGES;

    // ws: hs bf16 [N*128] | z1 bf16 [N*128] | srcPerm [E] | dinv [N] | offs [N]
    //     | cnt [N] | bsum [256]     (~28.6 MB total)
    ushort* hs      = (ushort*)d_ws;
    ushort* z1      = hs + (size_t)N_NODES * HID;
    int*    srcPerm = (int*)(z1 + (size_t)N_NODES * HID);
    float*  dinv    = (float*)(srcPerm + N_EDGES);
    int*    offs    = (int*)(dinv + N_NODES);
    int*    cnt     = offs + N_NODES;
    int*    bsum    = cnt + N_NODES;

    const int B = 256;
    const int nodeB = (N_NODES + B - 1) / B;            // 196
    const int edgeB = (N_EDGES + B - 1) / B;
    const int gemm_blocks    = (N_NODES + 63) / 64;     // 782
    const int rowwave_blocks = (N_NODES + 3) / 4;       // 1 wave per node

    // degree -> dinv, CSR build
    zero_cnt_kernel<<<nodeB, B, 0, stream>>>(cnt, N_NODES);
    count_deg_kernel<<<edgeB, B, 0, stream>>>(dst, cnt, N_EDGES);
    reduce_dinv_kernel<<<nodeB, B, 0, stream>>>(cnt, dinv, bsum, N_NODES);
    scan_bsum_kernel<<<1, B, 0, stream>>>(bsum, nodeB);
    scan_block_kernel<<<nodeB, B, 0, stream>>>(cnt, bsum, offs, N_NODES);
    fill_csr_kernel<<<edgeB, B, 0, stream>>>(src, dst, offs, srcPerm, N_EDGES);
    // post-fill: offs[d] == end of segment d

    // ---- layer 1 ----
    gemm_mfma_kernel<true><<<gemm_blocks, B, 0, stream>>>(
        x, W1, dinv, hs, N_NODES);
    agg_ln_gelu_kernel<false><<<rowwave_blocks, B, 0, stream>>>(
        (const uint*)hs, dinv, offs, srcPerm, b1, g1, be1,
        nullptr, (uint*)z1, N_NODES);

    // ---- layer 2 ----
    gemm_mfma_kernel<false><<<gemm_blocks, B, 0, stream>>>(
        z1, W2, dinv, hs, N_NODES);
    agg_ln_gelu_kernel<true><<<rowwave_blocks, B, 0, stream>>>(
        (const uint*)hs, dinv, offs, srcPerm, b2, g2, be2,
        out, nullptr, N_NODES);
}